// Round 3
// baseline (1234.739 us; speedup 1.0000x reference)
//
#include <hip/hip_runtime.h>
#include <math.h>

#define N_NODES_C 50000
#define N_GRAPHS_C 64
#define HDIM 128

typedef short bf16x8 __attribute__((ext_vector_type(8)));
typedef short shortx4 __attribute__((ext_vector_type(4)));
typedef float floatx4 __attribute__((ext_vector_type(4)));

// split f32 -> hi (truncated bf16) + lo (bf16 of exact residual)
__device__ __forceinline__ void cvt_pair(float x, short& h, short& l) {
    union { float f; unsigned u; } a; a.f = x;
    h = (short)(a.u >> 16);
    union { unsigned u; float f; } b; b.u = a.u & 0xFFFF0000u;
    union { float f; unsigned u; } c; c.f = x - b.f;   // exact residual
    l = (short)(c.u >> 16);
}

__device__ __forceinline__ float b2f(short s) {
    union { unsigned u; float f; } x; x.u = ((unsigned)(unsigned short)s) << 16;
    return x.f;
}

// ============ MFMA GEMM — NO LDS (R3) ============
// C[M,N] = A[M,K] @ BT[N,K]^T (+bias). A: f32 (AF32=1) or bf16 hi/lo planes.
// B: always bf16 hi/lo planes. Split-bf16 3-MFMA for f32-class accuracy.
// mode 0: Cf32 = v + bias          (ldc = Ntot)
// mode 2: planes = relu(v + bias)  (ldc = 128)
// mode 3: planes = relu(gate*v+bias' + (1-gate)*prev)  (ldc = 128)
//
// Rationale: B has ZERO intra-block reuse (1.3 MB, L2-resident) and A only 2x
// (served by L1); LDS staging was pure overhead and its barrier convoy pinned
// the kernel at 178+ us across three schedules. Fragments now load straight
// from global/L2, rotated 2-deep with two NAMED register sets (no runtime
// indexing -> no scratch), zero barriers. Each fragment load: 64 lanes x 16 B
// = 16 full 64-B lines (quads cover consecutive granules of the same row).
#define GBM 128
#define GBN 128
#define GBK 32

template<int AF32>
__global__ __launch_bounds__(256, 2) void gemm_planes(
    const void* __restrict__ Aptr, const short* __restrict__ Alo, int lda,
    const short* __restrict__ Bhi, const short* __restrict__ Blo, int ldbt,
    const float* __restrict__ bias,
    float* __restrict__ Cf, short* __restrict__ Chi, short* __restrict__ Clo,
    int M, int Ntot, int K,
    int mode, const float* __restrict__ skipGate,
    const short* __restrict__ Phi, const short* __restrict__ Plo)
{
    const int t = threadIdx.x;
    const int lane = t & 63;
    const int wave = t >> 6;
    const int wm = wave & 1, wn = wave >> 1;
    const int quad = lane >> 4, l15 = lane & 15;

    // XCD-bijective chunked swizzle (valid for any nwg), column-fastest decode
    const int nwg = gridDim.x, bid0 = blockIdx.x;
    const int qq = nwg >> 3, rr = nwg & 7;
    const int xcd = bid0 & 7, idx = bid0 >> 3;
    const int swz = (xcd < rr ? xcd * (qq + 1)
                              : rr * (qq + 1) + (xcd - rr) * qq) + idx;
    const int ncb = (Ntot + GBN - 1) / GBN;
    const long row0 = (long)(swz / ncb) * GBM;
    const long col0 = (long)(swz % ncb) * GBN;

    // per-lane fragment base offsets (element units); compile-time indexed only
    long aoff[4], boff[4];
    #pragma unroll
    for (int i = 0; i < 4; ++i) {
        long r = row0 + wm * 64 + i * 16 + l15;
        if (r > M - 1) r = M - 1;
        aoff[i] = r * (long)lda + quad * 8;
    }
    #pragma unroll
    for (int j = 0; j < 4; ++j) {
        long c = col0 + wn * 64 + j * 16 + l15;
        if (c > Ntot - 1) c = Ntot - 1;
        boff[j] = c * (long)ldbt + quad * 8;
    }

    floatx4 acc[4][4];
    #pragma unroll
    for (int i = 0; i < 4; ++i)
        #pragma unroll
        for (int j = 0; j < 4; ++j)
            acc[i][j] = (floatx4){0.f, 0.f, 0.f, 0.f};

    const int nkt = K / GBK;   // 16 or 4 here -> always even

    if constexpr (AF32) {
        const float* Af = (const float*)Aptr;
        float4 fA0[8], fA1[8];
        bf16x8 bH0[4], bL0[4], bH1[4], bL1[4];

        auto LD = [&](int k0, float4* fA, bf16x8* bH, bf16x8* bL) {
            #pragma unroll
            for (int i = 0; i < 4; ++i) {
                const float* p = Af + aoff[i] + k0;
                fA[2 * i]     = *(const float4*)p;
                fA[2 * i + 1] = *(const float4*)(p + 4);
            }
            #pragma unroll
            for (int j = 0; j < 4; ++j) {
                bH[j] = *(const bf16x8*)(Bhi + boff[j] + k0);
                bL[j] = *(const bf16x8*)(Blo + boff[j] + k0);
            }
        };
        auto STEP = [&](const float4* fA, const bf16x8* bH, const bf16x8* bL) {
            #pragma unroll
            for (int i = 0; i < 4; ++i) {
                // convert this row-fragment just-in-time (keeps reg pressure low)
                short h0,h1,h2,h3,h4,h5,h6,h7, l0,l1,l2,l3,l4,l5,l6,l7;
                cvt_pair(fA[2*i].x,  h0,l0); cvt_pair(fA[2*i].y,  h1,l1);
                cvt_pair(fA[2*i].z,  h2,l2); cvt_pair(fA[2*i].w,  h3,l3);
                cvt_pair(fA[2*i+1].x,h4,l4); cvt_pair(fA[2*i+1].y,h5,l5);
                cvt_pair(fA[2*i+1].z,h6,l6); cvt_pair(fA[2*i+1].w,h7,l7);
                bf16x8 aH = (bf16x8){h0,h1,h2,h3,h4,h5,h6,h7};
                bf16x8 aL = (bf16x8){l0,l1,l2,l3,l4,l5,l6,l7};
                #pragma unroll
                for (int j = 0; j < 4; ++j) {
                    acc[i][j] = __builtin_amdgcn_mfma_f32_16x16x32_bf16(aH, bH[j], acc[i][j], 0, 0, 0);
                    acc[i][j] = __builtin_amdgcn_mfma_f32_16x16x32_bf16(aH, bL[j], acc[i][j], 0, 0, 0);
                    acc[i][j] = __builtin_amdgcn_mfma_f32_16x16x32_bf16(aL, bH[j], acc[i][j], 0, 0, 0);
                }
            }
        };

        LD(0, fA0, bH0, bL0);
        for (int kt = 0; kt < nkt; kt += 2) {
            LD((kt + 1) * GBK, fA1, bH1, bL1);      // prefetch odd tile
            STEP(fA0, bH0, bL0);                    // compute even tile
            if (kt + 2 < nkt) LD((kt + 2) * GBK, fA0, bH0, bL0);
            STEP(fA1, bH1, bL1);                    // compute odd tile
        }
    } else {
        const short* Ahi = (const short*)Aptr;
        bf16x8 aH0[4], aL0[4], bH0[4], bL0[4];
        bf16x8 aH1[4], aL1[4], bH1[4], bL1[4];

        auto LD = [&](int k0, bf16x8* aH, bf16x8* aL, bf16x8* bH, bf16x8* bL) {
            #pragma unroll
            for (int i = 0; i < 4; ++i) {
                aH[i] = *(const bf16x8*)(Ahi + aoff[i] + k0);
                aL[i] = *(const bf16x8*)(Alo + aoff[i] + k0);
            }
            #pragma unroll
            for (int j = 0; j < 4; ++j) {
                bH[j] = *(const bf16x8*)(Bhi + boff[j] + k0);
                bL[j] = *(const bf16x8*)(Blo + boff[j] + k0);
            }
        };
        auto STEP = [&](const bf16x8* aH, const bf16x8* aL,
                        const bf16x8* bH, const bf16x8* bL) {
            #pragma unroll
            for (int i = 0; i < 4; ++i)
                #pragma unroll
                for (int j = 0; j < 4; ++j) {
                    acc[i][j] = __builtin_amdgcn_mfma_f32_16x16x32_bf16(aH[i], bH[j], acc[i][j], 0, 0, 0);
                    acc[i][j] = __builtin_amdgcn_mfma_f32_16x16x32_bf16(aH[i], bL[j], acc[i][j], 0, 0, 0);
                    acc[i][j] = __builtin_amdgcn_mfma_f32_16x16x32_bf16(aL[i], bH[j], acc[i][j], 0, 0, 0);
                }
        };

        LD(0, aH0, aL0, bH0, bL0);
        for (int kt = 0; kt < nkt; kt += 2) {
            LD((kt + 1) * GBK, aH1, aL1, bH1, bL1);
            STEP(aH0, aL0, bH0, bL0);
            if (kt + 2 < nkt) LD((kt + 2) * GBK, aH0, aL0, bH0, bL0);
            STEP(aH1, aL1, bH1, bL1);
        }
    }

    float gate = 0.f;
    if (mode == 3) gate = 1.f / (1.f + __expf(-skipGate[0]));

    #pragma unroll
    for (int i = 0; i < 4; ++i) {
        #pragma unroll
        for (int r4 = 0; r4 < 4; ++r4) {
            long grow = row0 + wm * 64 + i * 16 + quad * 4 + r4;
            if (grow >= M) continue;
            #pragma unroll
            for (int j = 0; j < 4; ++j) {
                long gcol = col0 + wn * 64 + j * 16 + l15;
                if (gcol >= Ntot) continue;
                float v = acc[i][j][r4];
                if (bias) v += bias[gcol];
                if (mode == 0) {
                    Cf[grow * Ntot + gcol] = v;
                } else {
                    if (mode == 3) {
                        long po = grow * 128 + gcol;
                        float pv = b2f(Phi[po]) + b2f(Plo[po]);
                        v = gate * v + (1.f - gate) * pv;
                    }
                    v = fmaxf(v, 0.f);
                    short hh, ll; cvt_pair(v, hh, ll);
                    Chi[grow * 128 + gcol] = hh;
                    Clo[grow * 128 + gcol] = ll;
                }
            }
        }
    }
}

// ============ build fused WbigT[640, F] as bf16 hi/lo planes + bias640 ============
// cols: [0,128) q | [128,384) k_r | [384,640) v_r ; one c per blockIdx.y
__global__ __launch_bounds__(256) void build_wbigT_p(
    const float* __restrict__ Wq, const float* __restrict__ bq,
    const float* __restrict__ Wk, const float* __restrict__ bk,
    const float* __restrict__ Wv, const float* __restrict__ bv,
    const float* __restrict__ arel, const float* __restrict__ mrel,
    short* __restrict__ WThi, short* __restrict__ WTlo,
    float* __restrict__ bias, int F)
{
    __shared__ float Trow[64];
    int c = blockIdx.y;
    int f = blockIdx.x * 256 + threadIdx.x;
    float w = 0.f, b = 0.f;
    if (c < 128) {
        if (f < F) w = Wq[(long)f * 128 + c];
        b = bq[c];
    } else {
        int cc = c - 128;
        const float* Wsrc; const float* bsrc; const float* T;
        if (cc < 256) { Wsrc = Wk; bsrc = bk; T = arel; }
        else { cc -= 256; Wsrc = Wv; bsrc = bv; T = mrel; }
        int r = cc >> 7, j = cc & 127, h = j >> 6, e = j & 63;
        const float* Tr = T + (long)(r * 2 + h) * 4096 + e;
        if (threadIdx.x < 64) Trow[threadIdx.x] = Tr[(long)threadIdx.x * 64];
        __syncthreads();
        if (f < F) {
            const float* Wrow = Wsrc + (long)f * 128 + h * 64;
            float s = 0.f;
            #pragma unroll 4
            for (int d = 0; d < 64; ++d) s = fmaf(Wrow[d], Trow[d], s);
            w = s;
        }
        if (f == 0) {
            const float* brow = bsrc + h * 64;
            float sb = 0.f;
            for (int d = 0; d < 64; ++d) sb = fmaf(brow[d], Trow[d], sb);
            b = sb;
        }
    }
    if (f < F) {
        short hh, ll; cvt_pair(w, hh, ll);
        WThi[(long)c * F + f] = hh;
        WTlo[(long)c * F + f] = ll;
    }
    if (f == 0) bias[c] = b;
}

// W[128,128] -> WT planes [128,128] bf16 hi/lo
__global__ void transpose128p(const float* __restrict__ W,
                              short* __restrict__ hi, short* __restrict__ lo)
{
    int idx = blockIdx.x * 256 + threadIdx.x;   // 16384
    int c = idx >> 7, f = idx & 127;
    short hh, ll; cvt_pair(W[f * 128 + c], hh, ll);
    hi[idx] = hh; lo[idx] = ll;
}

// ============ CSR build, both relations per launch (blockIdx.y = r) ============
__global__ void csr_count2(const int* __restrict__ e0p, const int* __restrict__ e1p,
                           int* __restrict__ counts, int E, int N)
{
    int e = blockIdx.x * 256 + threadIdx.x;
    int r = blockIdx.y;
    const int* dst = (r ? e1p : e0p) + E;
    if (e < E) atomicAdd(&counts[r * N + dst[e]], 1);
}

__global__ __launch_bounds__(1024) void csr_scan2(
    const int* __restrict__ counts,
    int* __restrict__ off0, int* __restrict__ off1,
    int* __restrict__ cursor, int N, int E)
{
    __shared__ int part[1024];
    int r = blockIdx.x;
    const int* cnt = counts + (long)r * N;
    int* offs = r ? off1 : off0;
    int* cur  = cursor + (long)r * N;
    int t = threadIdx.x;
    int chunk = (N + 1023) / 1024;
    int a = t * chunk, b = a + chunk; if (b > N) b = N;
    int s = 0;
    for (int i = a; i < b; ++i) s += cnt[i];
    part[t] = s;
    __syncthreads();
    for (int off = 1; off < 1024; off <<= 1) {
        int v = (t >= off) ? part[t - off] : 0;
        __syncthreads();
        if (t >= off) part[t] += v;
        __syncthreads();
    }
    int p = (t == 0) ? 0 : part[t - 1];
    for (int i = a; i < b; ++i) {
        offs[i] = p; cur[i] = p; p += cnt[i];
    }
    if (t == 1023) offs[N] = E;
}

__global__ void csr_fill2(const int* __restrict__ e0p, const int* __restrict__ e1p,
                          int* __restrict__ cursor,
                          int* __restrict__ ss0, int* __restrict__ ss1, int E, int N)
{
    int e = blockIdx.x * 256 + threadIdx.x;
    if (e >= E) return;
    int r = blockIdx.y;
    const int* ed = r ? e1p : e0p;
    int* ss = r ? ss1 : ss0;
    int pos = atomicAdd(&cursor[r * N + ed[E + e]], 1);
    ss[pos] = ed[e];
}

// ============ node attention: one wave per (node, head) ============
__global__ __launch_bounds__(256) void node_attn_kernel(
    const float* __restrict__ qkv,
    const int* __restrict__ off0, const int* __restrict__ ss0,
    const int* __restrict__ off1, const int* __restrict__ ss1,
    const float* __restrict__ prel,     // [2][2] (r,h)
    short* __restrict__ ohi, short* __restrict__ olo, int N)
{
    int wid = blockIdx.x * 4 + (threadIdx.x >> 6);
    int lane = threadIdx.x & 63;
    int d = wid >> 1, h = wid & 1;
    if (d >= N) return;
    int g = lane >> 4, l = lane & 15;

    float4 q4 = *(const float4*)(qkv + (long)d * 640 + h * 64 + l * 4);

    int c0 = off0[d], b0 = off0[d + 1];
    int c1 = off1[d], b1 = off1[d + 1];
    const float* kp0 = qkv + 128 + h * 64 + l * 4;
    const float* vp0 = qkv + 384 + h * 64 + l * 4;
    const float* kp1 = kp0 + 128;
    const float* vp1 = vp0 + 128;
    float pr0 = prel[h] * 0.125f;       // includes 1/sqrt(64)
    float pr1 = prel[2 + h] * 0.125f;

    const float4 fz = {0.f, 0.f, 0.f, 0.f};
    float4 num0 = fz, num1 = fz;
    float den0 = 0.f, den1 = 0.f;

    while (c0 < b0 || c1 < b1) {
        float4 k0 = fz, v0 = fz, k1 = fz, v1 = fz;
        bool a0 = (c0 < b0) && (c0 + g < b0);
        bool a1 = (c1 < b1) && (c1 + g < b1);
        if (a0) {
            long so = (long)ss0[c0 + g] * 640;
            k0 = *(const float4*)(kp0 + so);
            v0 = *(const float4*)(vp0 + so);
        }
        if (a1) {
            long so = (long)ss1[c1 + g] * 640;
            k1 = *(const float4*)(kp1 + so);
            v1 = *(const float4*)(vp1 + so);
        }
        if (c0 < b0) {
            float p = q4.x*k0.x + q4.y*k0.y + q4.z*k0.z + q4.w*k0.w;
            p += __shfl_xor(p, 1, 16);
            p += __shfl_xor(p, 2, 16);
            p += __shfl_xor(p, 4, 16);
            p += __shfl_xor(p, 8, 16);
            float w = a0 ? __expf(p * pr0) : 0.f;
            den0 += w;
            num0.x = fmaf(w, v0.x, num0.x);
            num0.y = fmaf(w, v0.y, num0.y);
            num0.z = fmaf(w, v0.z, num0.z);
            num0.w = fmaf(w, v0.w, num0.w);
            c0 += 4;
        }
        if (c1 < b1) {
            float p = q4.x*k1.x + q4.y*k1.y + q4.z*k1.z + q4.w*k1.w;
            p += __shfl_xor(p, 1, 16);
            p += __shfl_xor(p, 2, 16);
            p += __shfl_xor(p, 4, 16);
            p += __shfl_xor(p, 8, 16);
            float w = a1 ? __expf(p * pr1) : 0.f;
            den1 += w;
            num1.x = fmaf(w, v1.x, num1.x);
            num1.y = fmaf(w, v1.y, num1.y);
            num1.z = fmaf(w, v1.z, num1.z);
            num1.w = fmaf(w, v1.w, num1.w);
            c1 += 4;
        }
    }

    #pragma unroll
    for (int o = 16; o <= 32; o <<= 1) {
        num0.x += __shfl_xor(num0.x, o, 64); num0.y += __shfl_xor(num0.y, o, 64);
        num0.z += __shfl_xor(num0.z, o, 64); num0.w += __shfl_xor(num0.w, o, 64);
        den0   += __shfl_xor(den0,   o, 64);
        num1.x += __shfl_xor(num1.x, o, 64); num1.y += __shfl_xor(num1.y, o, 64);
        num1.z += __shfl_xor(num1.z, o, 64); num1.w += __shfl_xor(num1.w, o, 64);
        den1   += __shfl_xor(den1,   o, 64);
    }
    float inv0 = 1.f / (den0 + 1e-16f);
    float inv1 = 1.f / (den1 + 1e-16f);
    float4 accv;
    accv.x = num0.x * inv0 + num1.x * inv1;
    accv.y = num0.y * inv0 + num1.y * inv1;
    accv.z = num0.z * inv0 + num1.z * inv1;
    accv.w = num0.w * inv0 + num1.w * inv1;

    if (g == 0) {
        const float is2 = 0.70710678118654752f;
        float o0 = 0.5f * accv.x * (1.f + erff(accv.x * is2));
        float o1 = 0.5f * accv.y * (1.f + erff(accv.y * is2));
        float o2 = 0.5f * accv.z * (1.f + erff(accv.z * is2));
        float o3 = 0.5f * accv.w * (1.f + erff(accv.w * is2));
        short h0,h1,h2,h3, l0,l1,l2,l3;
        cvt_pair(o0,h0,l0); cvt_pair(o1,h1,l1);
        cvt_pair(o2,h2,l2); cvt_pair(o3,h3,l3);
        long oo = (long)d * 128 + h * 64 + l * 4;
        *(shortx4*)(ohi + oo) = (shortx4){h0,h1,h2,h3};
        *(shortx4*)(olo + oo) = (shortx4){l0,l1,l2,l3};
    }
}

// ============ f32 vector GEMM kept for tiny MLP ============
#define BM 64
#define BN 64
#define BK 16
__global__ __launch_bounds__(256) void gemm_bias_kernel(
    const float* __restrict__ A, int lda,
    const float* __restrict__ B, int ldb,
    const float* __restrict__ bias,
    float* __restrict__ C, int ldc,
    int M, int K, int epilogue)
{
    __shared__ float As[BK][BM + 4];
    __shared__ float Bs[BK][BN + 4];
    const int t = threadIdx.x;
    const int row0 = blockIdx.y * BM;
    const int col0 = blockIdx.x * BN;
    const int tm = (t >> 4) << 2;
    const int tn = (t & 15) << 2;
    float acc[4][4] = {};
    for (int k0 = 0; k0 < K; k0 += BK) {
        #pragma unroll
        for (int i = 0; i < 4; ++i) {
            int idx = t + i * 256;
            int m = idx >> 4, kk = idx & 15;
            int gm = row0 + m;
            As[kk][m] = (gm < M) ? A[(long)gm * lda + (k0 + kk)] : 0.f;
        }
        #pragma unroll
        for (int i = 0; i < 4; ++i) {
            int idx = t + i * 256;
            int kk = idx >> 6, n = idx & 63;
            Bs[kk][n] = B[(long)(k0 + kk) * ldb + (col0 + n)];
        }
        __syncthreads();
        #pragma unroll
        for (int kk = 0; kk < BK; ++kk) {
            float a[4], b[4];
            #pragma unroll
            for (int i = 0; i < 4; ++i) a[i] = As[kk][tm + i];
            #pragma unroll
            for (int j = 0; j < 4; ++j) b[j] = Bs[kk][tn + j];
            #pragma unroll
            for (int i = 0; i < 4; ++i)
                #pragma unroll
                for (int j = 0; j < 4; ++j)
                    acc[i][j] = fmaf(a[i], b[j], acc[i][j]);
        }
        __syncthreads();
    }
    #pragma unroll
    for (int i = 0; i < 4; ++i) {
        int gm = row0 + tm + i;
        if (gm >= M) continue;
        #pragma unroll
        for (int j = 0; j < 4; ++j) {
            int gn = col0 + tn + j;
            float v = acc[i][j];
            if (bias) v += bias[gn];
            if (epilogue >= 1) v = fmaxf(v, 0.f);
            C[(long)gm * ldc + gn] = v;
        }
    }
}

// ============ pooling (reads bf16 hi/lo planes) ============
__device__ inline int lower_bound_i(const int* __restrict__ a, int n, int v)
{
    int lo = 0, hi = n;
    while (lo < hi) { int mid = (lo + hi) >> 1; if (a[mid] < v) lo = mid + 1; else hi = mid; }
    return lo;
}

__global__ void pool_kernel(const short* __restrict__ hhi, const short* __restrict__ hlo,
                            const int* __restrict__ batch,
                            float* __restrict__ s, int N)
{
    int g = blockIdx.x, part = blockIdx.y, c = threadIdx.x;
    int start = lower_bound_i(batch, N, g);
    int end = lower_bound_i(batch, N, g + 1);
    int cnt = end - start, parts = gridDim.y;
    int chunk = (cnt + parts - 1) / parts;
    int a = start + part * chunk;
    int b = a + chunk; if (b > end) b = end;
    if (a >= b) return;
    float sum = 0.f;
    for (int n = a; n < b; ++n) {
        long o = (long)n * HDIM + c;
        sum += b2f(hhi[o]) + b2f(hlo[o]);
    }
    atomicAdd(&s[g * HDIM + c], sum);
}

__global__ void pool_finalize(const float* __restrict__ s, const int* __restrict__ batch,
                              float* __restrict__ g_out, int N)
{
    int g = blockIdx.x, c = threadIdx.x;
    int start = lower_bound_i(batch, N, g);
    int end = lower_bound_i(batch, N, g + 1);
    float cnt = (float)((end - start) > 1 ? (end - start) : 1);
    g_out[g * HDIM + c] = s[g * HDIM + c] / cnt;
}

// ============ host ============
extern "C" void kernel_launch(void* const* d_in, const int* in_sizes, int n_in,
                              void* d_out, int out_size, void* d_ws, size_t ws_size,
                              hipStream_t stream)
{
    const float* x      = (const float*)d_in[0];
    const int*   e0     = (const int*)d_in[1];
    const int*   e1     = (const int*)d_in[2];
    const int*   batch  = (const int*)d_in[3];
    const float* W_k1   = (const float*)d_in[4];
    const float* W_q1   = (const float*)d_in[5];
    const float* W_v1   = (const float*)d_in[6];
    const float* a_rel1 = (const float*)d_in[7];
    const float* m_rel1 = (const float*)d_in[8];
    const float* W_a1   = (const float*)d_in[9];
    const float* W_k23  = (const float*)d_in[10];
    const float* W_q23  = (const float*)d_in[11];
    const float* W_v23  = (const float*)d_in[12];
    const float* a_rel23= (const float*)d_in[13];
    const float* m_rel23= (const float*)d_in[14];
    const float* W_a23  = (const float*)d_in[15];
    const float* W_m1   = (const float*)d_in[16];
    const float* W_m2   = (const float*)d_in[17];
    const float* b_k1   = (const float*)d_in[18];
    const float* b_q1   = (const float*)d_in[19];
    const float* b_v1   = (const float*)d_in[20];
    const float* b_a1   = (const float*)d_in[21];
    const float* b_k23  = (const float*)d_in[22];
    const float* b_q23  = (const float*)d_in[23];
    const float* b_v23  = (const float*)d_in[24];
    const float* b_a23  = (const float*)d_in[25];
    const float* skip23 = (const float*)d_in[26];
    const float* b_m1   = (const float*)d_in[27];
    const float* b_m2   = (const float*)d_in[28];
    const float* p_rel1 = (const float*)d_in[29];
    const float* p_rel23= (const float*)d_in[30];

    const int N = N_NODES_C;
    const int E = in_sizes[1] / 2;
    const int F = in_sizes[0] / N;            // 512
    const long NP = (long)N * HDIM;           // 6.4M plane elements

    // ---- workspace layout ----
    float* ws    = (float*)d_ws;
    float* QKV   = ws;                                  // N*640 f32 (128 MB)
    short* ACChi = (short*)(QKV + (long)N * 640);       // 6 planes, 12.8 MB each
    short* ACClo = ACChi + NP;
    short* H1hi  = ACClo + NP;
    short* H1lo  = H1hi + NP;
    short* H2hi  = H1lo + NP;
    short* H2lo  = H2hi + NP;
    short* WThi  = H2lo + NP;                           // 640*512 max
    short* WTlo  = WThi + 640 * 512;
    short* WaThi = WTlo + 640 * 512;                    // 128*128
    short* WaTlo = WaThi + 128 * 128;
    float* B640  = (float*)(WaTlo + 128 * 128);         // 640
    float* S     = B640 + 640;
    float* GM    = S + N_GRAPHS_C * HDIM;
    float* M1    = GM + N_GRAPHS_C * HDIM;
    int*   off0  = (int*)(M1 + N_GRAPHS_C * HDIM);      // N+1
    int*   ss0   = off0 + (N + 1);                      // E
    int*   off1  = ss0 + E;                             // N+1
    int*   ss1   = off1 + (N + 1);                      // E
    int*   counts = (int*)QKV;                          // 2N, alias: dead before QKV written
    int*   cursor = counts + 2 * N;                     // 2N
    size_t needed = (size_t)((char*)(ss1 + E) - (char*)d_ws);
    if (ws_size < needed) return;

    // ---- build CSR once, both relations per launch ----
    {
        int eb = (E + 255) / 256;
        hipMemsetAsync(counts, 0, (size_t)(2 * N) * sizeof(int), stream);
        dim3 cg(eb, 2);
        csr_count2<<<cg, 256, 0, stream>>>(e0, e1, counts, E, N);
        csr_scan2<<<2, 1024, 0, stream>>>(counts, off0, off1, cursor, N, E);
        csr_fill2<<<cg, 256, 0, stream>>>(e0, e1, cursor, ss0, ss1, E, N);
    }

    const int nrb = (N + GBM - 1) / GBM;   // 391 row blocks

    auto run_layer = [&](const void* Ain, const short* AinLo, int AF, int Fin,
                         const float* Wk, const float* bk,
                         const float* Wq, const float* bq,
                         const float* Wv, const float* bv,
                         const float* arel, const float* mrel, const float* prel,
                         const float* Wa, const float* ba,
                         const float* gate, const short* skipHi, const short* skipLo,
                         short* outHi, short* outLo) {
        dim3 bg((Fin + 255) / 256, 640);
        build_wbigT_p<<<bg, 256, 0, stream>>>(Wq, bq, Wk, bk, Wv, bv,
                                              arel, mrel, WThi, WTlo, B640, Fin);
        int qb = (640 / GBN) * nrb;        // 1D grid, XCD-swizzled in-kernel
        if (AF)
            gemm_planes<1><<<qb, 256, 0, stream>>>(Ain, nullptr, Fin, WThi, WTlo, Fin,
                B640, QKV, nullptr, nullptr, N, 640, Fin, 0, nullptr, nullptr, nullptr);
        else
            gemm_planes<0><<<qb, 256, 0, stream>>>(Ain, AinLo, Fin, WThi, WTlo, Fin,
                B640, QKV, nullptr, nullptr, N, 640, Fin, 0, nullptr, nullptr, nullptr);

        node_attn_kernel<<<(N * 2 + 3) / 4, 256, 0, stream>>>(
            QKV, off0, ss0, off1, ss1, prel, ACChi, ACClo, N);

        transpose128p<<<64, 256, 0, stream>>>(Wa, WaThi, WaTlo);
        gemm_planes<0><<<nrb, 256, 0, stream>>>(ACChi, ACClo, 128, WaThi, WaTlo, 128,
            ba, nullptr, outHi, outLo, N, 128, 128,
            gate ? 3 : 2, gate, skipHi, skipLo);
    };

    // layer 1 (f32 x input, no skip) -> H1 planes
    run_layer(x, nullptr, 1, F, W_k1, b_k1, W_q1, b_q1, W_v1, b_v1,
              a_rel1, m_rel1, p_rel1, W_a1, b_a1,
              nullptr, nullptr, nullptr, H1hi, H1lo);
    // layer 2 (H1 planes, gated skip from H1) -> H2 planes
    run_layer(H1hi, H1lo, 0, HDIM, W_k23, b_k23, W_q23, b_q23, W_v23, b_v23,
              a_rel23, m_rel23, p_rel23, W_a23, b_a23,
              skip23, H1hi, H1lo, H2hi, H2lo);
    // layer 3 (H2 planes, gated skip from H2) -> H1 planes (reuse)
    run_layer(H2hi, H2lo, 0, HDIM, W_k23 + 16384, b_k23 + 128, W_q23 + 16384, b_q23 + 128,
              W_v23 + 16384, b_v23 + 128, a_rel23 + 16384, m_rel23 + 16384,
              p_rel23 + 4, W_a23 + 16384, b_a23 + 128,
              skip23 + 1, H2hi, H2lo, H1hi, H1lo);

    // global mean pool (batch sorted)
    hipMemsetAsync(S, 0, (size_t)N_GRAPHS_C * HDIM * sizeof(float), stream);
    dim3 pg(N_GRAPHS_C, 8);
    pool_kernel<<<pg, HDIM, 0, stream>>>(H1hi, H1lo, batch, S, N);
    pool_finalize<<<N_GRAPHS_C, HDIM, 0, stream>>>(S, batch, GM, N);

    // MLP
    {
        dim3 g1(128 / BN, 1);
        gemm_bias_kernel<<<g1, 256, 0, stream>>>(GM, 128, W_m1, 128, b_m1, M1, 128,
                                                 N_GRAPHS_C, 128, 1);
        dim3 g2(256 / BN, 1);
        gemm_bias_kernel<<<g2, 256, 0, stream>>>(M1, 128, W_m2, 256, b_m2,
                                                 (float*)d_out, 256, N_GRAPHS_C, 128, 0);
    }
}

// Round 4
// 1012.090 us; speedup vs baseline: 1.2200x; 1.2200x over previous
//
#include <hip/hip_runtime.h>
#include <math.h>

#define N_NODES_C 50000
#define N_GRAPHS_C 64
#define HDIM 128

typedef short bf16x8 __attribute__((ext_vector_type(8)));
typedef short shortx4 __attribute__((ext_vector_type(4)));
typedef float floatx4 __attribute__((ext_vector_type(4)));

// split f32 -> hi (truncated bf16) + lo (bf16 of exact residual)
__device__ __forceinline__ void cvt_pair(float x, short& h, short& l) {
    union { float f; unsigned u; } a; a.f = x;
    h = (short)(a.u >> 16);
    union { unsigned u; float f; } b; b.u = a.u & 0xFFFF0000u;
    union { float f; unsigned u; } c; c.f = x - b.f;   // exact residual
    l = (short)(c.u >> 16);
}

__device__ __forceinline__ float b2f(short s) {
    union { unsigned u; float f; } x; x.u = ((unsigned)(unsigned short)s) << 16;
    return x.f;
}

// async global->LDS copy, 16 B per lane, LDS dest = wave-uniform base + lane*16
__device__ __forceinline__ void gld_lds16(const void* gsrc, void* ldst) {
    __builtin_amdgcn_global_load_lds(
        (const __attribute__((address_space(1))) unsigned int*)gsrc,
        (__attribute__((address_space(3))) unsigned int*)ldst,
        16, 0, 0);
}

// ============ MFMA GEMM with global_load_lds staging ============
// REVERTED to the R1 structure (measured 178 us for layer-1 QKV; best of 4
// schedule variants: R0 2-barrier=178, R1 dbuf+syncthreads=178, R2 raw
// barrier=210, R3 no-LDS=296). 2-phase double-buffer, one __syncthreads per
// k-tile, XCD-bijective swizzle (FETCH 270->74 MB).
// C[M,N] = A[M,K] @ BT[N,K]^T (+bias). A: f32 (AF32=1) or bf16 hi/lo planes.
// B: always bf16 hi/lo planes. Split-bf16 3-MFMA for f32-class accuracy.
// mode 0: Cf32 = v + bias          (ldc = Ntot)
// mode 2: planes = relu(v + bias)  (ldc = 128)
// mode 3: planes = relu(gate*v+bias' + (1-gate)*prev)  (ldc = 128)
#define GBM 128
#define GBN 128
#define GBK 32

template<int AF32>
__global__ __launch_bounds__(256, 2) void gemm_planes(
    const void* __restrict__ Aptr, const short* __restrict__ Alo, int lda,
    const short* __restrict__ Bhi, const short* __restrict__ Blo, int ldbt,
    const float* __restrict__ bias,
    float* __restrict__ Cf, short* __restrict__ Chi, short* __restrict__ Clo,
    int M, int Ntot, int K,
    int mode, const float* __restrict__ skipGate,
    const short* __restrict__ Phi, const short* __restrict__ Plo)
{
    constexpr int ASZ = AF32 ? (GBM * GBK * 2) : (GBM * GBK);  // shorts / buffer
    constexpr int BSZ = GBN * GBK;
    __shared__ __align__(16) short AsH[2 * ASZ];
    __shared__ __align__(16) short AsL[AF32 ? 8 : (2 * GBM * GBK)];
    __shared__ __align__(16) short BsH[2 * BSZ];
    __shared__ __align__(16) short BsL[2 * BSZ];

    const int t = threadIdx.x;
    const int lane = t & 63;
    const int wave = t >> 6;
    const int wm = wave & 1, wn = wave >> 1;
    const int quad = lane >> 4, l15 = lane & 15;

    // XCD-bijective chunked swizzle (valid for any nwg), column-fastest decode
    const int nwg = gridDim.x, bid0 = blockIdx.x;
    const int qq = nwg >> 3, rr = nwg & 7;
    const int xcd = bid0 & 7, idx = bid0 >> 3;
    const int swz = (xcd < rr ? xcd * (qq + 1)
                              : rr * (qq + 1) + (xcd - rr) * qq) + idx;
    const int ncb = (Ntot + GBN - 1) / GBN;
    const long row0 = (long)(swz / ncb) * GBM;
    const long col0 = (long)(swz % ncb) * GBN;

    floatx4 acc[4][4];
    #pragma unroll
    for (int i = 0; i < 4; ++i)
        #pragma unroll
        for (int j = 0; j < 4; ++j)
            acc[i][j] = (floatx4){0.f, 0.f, 0.f, 0.f};

    const int nkt = K / GBK;

    auto stage = [&](int buf, int k0) {
        if constexpr (AF32) {
            // f32 tile 128x32 = 16 KB, 16 chunks of 1 KB (8 rows each),
            // XOR-swizzled granules so fragment ds_reads are ~conflict-free
            const float* Af = (const float*)Aptr;
            int r8 = lane >> 3, kc8 = lane & 7;
            #pragma unroll
            for (int cc = 0; cc < 4; ++cc) {
                int ch = wave * 4 + cc;
                long gr = row0 + ch * 8 + r8;
                if (gr > M - 1) gr = M - 1;
                gld_lds16(Af + gr * lda + k0 + ((kc8 ^ r8) << 2),
                          AsH + buf * ASZ + ch * 512);
            }
        } else {
            const short* Ahi = (const short*)Aptr;
            int r16 = lane >> 2, g4 = lane & 3;
            #pragma unroll
            for (int cc = 0; cc < 2; ++cc) {
                int ch = wave * 2 + cc;
                long gr = row0 + ch * 16 + r16;
                if (gr > M - 1) gr = M - 1;
                long go = gr * lda + k0 + g4 * 8;
                gld_lds16(Ahi + go, AsH + buf * ASZ + ch * 512);
                gld_lds16(Alo + go, AsL + buf * ASZ + ch * 512);
            }
        }
        {
            int r16 = lane >> 2, g4 = lane & 3;
            #pragma unroll
            for (int cc = 0; cc < 2; ++cc) {
                int ch = wave * 2 + cc;
                long gc = col0 + ch * 16 + r16;
                if (gc > Ntot - 1) gc = Ntot - 1;
                long go = gc * ldbt + k0 + g4 * 8;
                gld_lds16(Bhi + go, BsH + buf * BSZ + ch * 512);
                gld_lds16(Blo + go, BsL + buf * BSZ + ch * 512);
            }
        }
    };

    stage(0, 0);          // prologue fill of buffer 0
    int cur = 0;

    for (int kt = 0; kt < nkt; ++kt) {
        // drains this wave's vmcnt (stage of buf 'cur' landed) + barrier;
        // also guarantees all waves finished reading buf cur^1 (iter kt-1)
        __syncthreads();
        if (kt + 1 < nkt) stage(cur ^ 1, (kt + 1) * GBK);   // prefetch next

        bf16x8 aH[4], aL[4], bH[4], bL[4];
        if constexpr (AF32) {
            #pragma unroll
            for (int i = 0; i < 4; ++i) {
                int row = wm * 64 + i * 16 + l15;
                const float* fr = (const float*)(AsH + cur * ASZ) + row * 32;
                int x7 = row & 7;
                float4 f0 = *(const float4*)(fr + (((quad * 2)     ^ x7) << 2));
                float4 f1 = *(const float4*)(fr + (((quad * 2 + 1) ^ x7) << 2));
                short h0,h1,h2,h3,h4,h5,h6,h7, l0,l1,l2,l3,l4,l5,l6,l7;
                cvt_pair(f0.x,h0,l0); cvt_pair(f0.y,h1,l1);
                cvt_pair(f0.z,h2,l2); cvt_pair(f0.w,h3,l3);
                cvt_pair(f1.x,h4,l4); cvt_pair(f1.y,h5,l5);
                cvt_pair(f1.z,h6,l6); cvt_pair(f1.w,h7,l7);
                aH[i] = (bf16x8){h0,h1,h2,h3,h4,h5,h6,h7};
                aL[i] = (bf16x8){l0,l1,l2,l3,l4,l5,l6,l7};
            }
        } else {
            #pragma unroll
            for (int i = 0; i < 4; ++i) {
                int off = cur * ASZ + (wm * 64 + i * 16 + l15) * 32 + quad * 8;
                aH[i] = *(const bf16x8*)&AsH[off];
                aL[i] = *(const bf16x8*)&AsL[off];
            }
        }
        #pragma unroll
        for (int j = 0; j < 4; ++j) {
            int off = cur * BSZ + (wn * 64 + j * 16 + l15) * 32 + quad * 8;
            bH[j] = *(const bf16x8*)&BsH[off];
            bL[j] = *(const bf16x8*)&BsL[off];
        }
        #pragma unroll
        for (int i = 0; i < 4; ++i)
            #pragma unroll
            for (int j = 0; j < 4; ++j) {
                acc[i][j] = __builtin_amdgcn_mfma_f32_16x16x32_bf16(aH[i], bH[j], acc[i][j], 0, 0, 0);
                acc[i][j] = __builtin_amdgcn_mfma_f32_16x16x32_bf16(aH[i], bL[j], acc[i][j], 0, 0, 0);
                acc[i][j] = __builtin_amdgcn_mfma_f32_16x16x32_bf16(aL[i], bH[j], acc[i][j], 0, 0, 0);
            }
        cur ^= 1;
    }

    float gate = 0.f;
    if (mode == 3) gate = 1.f / (1.f + __expf(-skipGate[0]));

    #pragma unroll
    for (int i = 0; i < 4; ++i) {
        #pragma unroll
        for (int r4 = 0; r4 < 4; ++r4) {
            long grow = row0 + wm * 64 + i * 16 + quad * 4 + r4;
            if (grow >= M) continue;
            #pragma unroll
            for (int j = 0; j < 4; ++j) {
                long gcol = col0 + wn * 64 + j * 16 + l15;
                if (gcol >= Ntot) continue;
                float v = acc[i][j][r4];
                if (bias) v += bias[gcol];
                if (mode == 0) {
                    Cf[grow * Ntot + gcol] = v;
                } else {
                    if (mode == 3) {
                        long po = grow * 128 + gcol;
                        float pv = b2f(Phi[po]) + b2f(Plo[po]);
                        v = gate * v + (1.f - gate) * pv;
                    }
                    v = fmaxf(v, 0.f);
                    short hh, ll; cvt_pair(v, hh, ll);
                    Chi[grow * 128 + gcol] = hh;
                    Clo[grow * 128 + gcol] = ll;
                }
            }
        }
    }
}

// ============ build fused WbigT[640, F] as bf16 hi/lo planes + bias640 ============
// cols: [0,128) q | [128,384) k_r | [384,640) v_r ; one c per blockIdx.y
__global__ __launch_bounds__(256) void build_wbigT_p(
    const float* __restrict__ Wq, const float* __restrict__ bq,
    const float* __restrict__ Wk, const float* __restrict__ bk,
    const float* __restrict__ Wv, const float* __restrict__ bv,
    const float* __restrict__ arel, const float* __restrict__ mrel,
    short* __restrict__ WThi, short* __restrict__ WTlo,
    float* __restrict__ bias, int F)
{
    __shared__ float Trow[64];
    int c = blockIdx.y;
    int f = blockIdx.x * 256 + threadIdx.x;
    float w = 0.f, b = 0.f;
    if (c < 128) {
        if (f < F) w = Wq[(long)f * 128 + c];
        b = bq[c];
    } else {
        int cc = c - 128;
        const float* Wsrc; const float* bsrc; const float* T;
        if (cc < 256) { Wsrc = Wk; bsrc = bk; T = arel; }
        else { cc -= 256; Wsrc = Wv; bsrc = bv; T = mrel; }
        int r = cc >> 7, j = cc & 127, h = j >> 6, e = j & 63;
        const float* Tr = T + (long)(r * 2 + h) * 4096 + e;
        if (threadIdx.x < 64) Trow[threadIdx.x] = Tr[(long)threadIdx.x * 64];
        __syncthreads();
        if (f < F) {
            const float* Wrow = Wsrc + (long)f * 128 + h * 64;
            float s = 0.f;
            #pragma unroll 4
            for (int d = 0; d < 64; ++d) s = fmaf(Wrow[d], Trow[d], s);
            w = s;
        }
        if (f == 0) {
            const float* brow = bsrc + h * 64;
            float sb = 0.f;
            for (int d = 0; d < 64; ++d) sb = fmaf(brow[d], Trow[d], sb);
            b = sb;
        }
    }
    if (f < F) {
        short hh, ll; cvt_pair(w, hh, ll);
        WThi[(long)c * F + f] = hh;
        WTlo[(long)c * F + f] = ll;
    }
    if (f == 0) bias[c] = b;
}

// W[128,128] -> WT planes [128,128] bf16 hi/lo
__global__ void transpose128p(const float* __restrict__ W,
                              short* __restrict__ hi, short* __restrict__ lo)
{
    int idx = blockIdx.x * 256 + threadIdx.x;   // 16384
    int c = idx >> 7, f = idx & 127;
    short hh, ll; cvt_pair(W[f * 128 + c], hh, ll);
    hi[idx] = hh; lo[idx] = ll;
}

// ============ CSR build, both relations per launch (blockIdx.y = r) ============
__global__ void csr_count2(const int* __restrict__ e0p, const int* __restrict__ e1p,
                           int* __restrict__ counts, int E, int N)
{
    int e = blockIdx.x * 256 + threadIdx.x;
    int r = blockIdx.y;
    const int* dst = (r ? e1p : e0p) + E;
    if (e < E) atomicAdd(&counts[r * N + dst[e]], 1);
}

__global__ __launch_bounds__(1024) void csr_scan2(
    const int* __restrict__ counts,
    int* __restrict__ off0, int* __restrict__ off1,
    int* __restrict__ cursor, int N, int E)
{
    __shared__ int part[1024];
    int r = blockIdx.x;
    const int* cnt = counts + (long)r * N;
    int* offs = r ? off1 : off0;
    int* cur  = cursor + (long)r * N;
    int t = threadIdx.x;
    int chunk = (N + 1023) / 1024;
    int a = t * chunk, b = a + chunk; if (b > N) b = N;
    int s = 0;
    for (int i = a; i < b; ++i) s += cnt[i];
    part[t] = s;
    __syncthreads();
    for (int off = 1; off < 1024; off <<= 1) {
        int v = (t >= off) ? part[t - off] : 0;
        __syncthreads();
        if (t >= off) part[t] += v;
        __syncthreads();
    }
    int p = (t == 0) ? 0 : part[t - 1];
    for (int i = a; i < b; ++i) {
        offs[i] = p; cur[i] = p; p += cnt[i];
    }
    if (t == 1023) offs[N] = E;
}

__global__ void csr_fill2(const int* __restrict__ e0p, const int* __restrict__ e1p,
                          int* __restrict__ cursor,
                          int* __restrict__ ss0, int* __restrict__ ss1, int E, int N)
{
    int e = blockIdx.x * 256 + threadIdx.x;
    if (e >= E) return;
    int r = blockIdx.y;
    const int* ed = r ? e1p : e0p;
    int* ss = r ? ss1 : ss0;
    int pos = atomicAdd(&cursor[r * N + ed[E + e]], 1);
    ss[pos] = ed[e];
}

// ============ node attention: one wave per (node, head) ============
// 16 lanes per edge, float4 gathers, BOTH relations interleaved in one loop.
// R4: epilogue reduction restructured — reduce den0/den1 across the 4 edge
// groups FIRST (4 shfls), combine numerators per-lane with the uniform
// inverses, then butterfly only the combined accv (8 shfls). 12 shfls vs 20
// (ds_bpermute is the DS-pipe cost driver at 100K waves/layer).
__global__ __launch_bounds__(256) void node_attn_kernel(
    const float* __restrict__ qkv,
    const int* __restrict__ off0, const int* __restrict__ ss0,
    const int* __restrict__ off1, const int* __restrict__ ss1,
    const float* __restrict__ prel,     // [2][2] (r,h)
    short* __restrict__ ohi, short* __restrict__ olo, int N)
{
    int wid = blockIdx.x * 4 + (threadIdx.x >> 6);
    int lane = threadIdx.x & 63;
    int d = wid >> 1, h = wid & 1;
    if (d >= N) return;
    int g = lane >> 4, l = lane & 15;

    float4 q4 = *(const float4*)(qkv + (long)d * 640 + h * 64 + l * 4);

    int c0 = off0[d], b0 = off0[d + 1];
    int c1 = off1[d], b1 = off1[d + 1];
    const float* kp0 = qkv + 128 + h * 64 + l * 4;
    const float* vp0 = qkv + 384 + h * 64 + l * 4;
    const float* kp1 = kp0 + 128;
    const float* vp1 = vp0 + 128;
    float pr0 = prel[h] * 0.125f;       // includes 1/sqrt(64)
    float pr1 = prel[2 + h] * 0.125f;

    const float4 fz = {0.f, 0.f, 0.f, 0.f};
    float4 num0 = fz, num1 = fz;
    float den0 = 0.f, den1 = 0.f;

    while (c0 < b0 || c1 < b1) {
        // issue all gathers for both relations first (overlapped latency)
        float4 k0 = fz, v0 = fz, k1 = fz, v1 = fz;
        bool a0 = (c0 < b0) && (c0 + g < b0);
        bool a1 = (c1 < b1) && (c1 + g < b1);
        if (a0) {
            long so = (long)ss0[c0 + g] * 640;
            k0 = *(const float4*)(kp0 + so);
            v0 = *(const float4*)(vp0 + so);
        }
        if (a1) {
            long so = (long)ss1[c1 + g] * 640;
            k1 = *(const float4*)(kp1 + so);
            v1 = *(const float4*)(vp1 + so);
        }
        if (c0 < b0) {
            float p = q4.x*k0.x + q4.y*k0.y + q4.z*k0.z + q4.w*k0.w;
            p += __shfl_xor(p, 1, 16);
            p += __shfl_xor(p, 2, 16);
            p += __shfl_xor(p, 4, 16);
            p += __shfl_xor(p, 8, 16);
            float w = a0 ? __expf(p * pr0) : 0.f;
            den0 += w;
            num0.x = fmaf(w, v0.x, num0.x);
            num0.y = fmaf(w, v0.y, num0.y);
            num0.z = fmaf(w, v0.z, num0.z);
            num0.w = fmaf(w, v0.w, num0.w);
            c0 += 4;
        }
        if (c1 < b1) {
            float p = q4.x*k1.x + q4.y*k1.y + q4.z*k1.z + q4.w*k1.w;
            p += __shfl_xor(p, 1, 16);
            p += __shfl_xor(p, 2, 16);
            p += __shfl_xor(p, 4, 16);
            p += __shfl_xor(p, 8, 16);
            float w = a1 ? __expf(p * pr1) : 0.f;
            den1 += w;
            num1.x = fmaf(w, v1.x, num1.x);
            num1.y = fmaf(w, v1.y, num1.y);
            num1.z = fmaf(w, v1.z, num1.z);
            num1.w = fmaf(w, v1.w, num1.w);
            c1 += 4;
        }
    }

    // (1) reduce denominators across the 4 edge groups (den is uniform
    //     within a group, so the 16/32 butterfly yields the global sum)
    #pragma unroll
    for (int o = 16; o <= 32; o <<= 1) {
        den0 += __shfl_xor(den0, o, 64);
        den1 += __shfl_xor(den1, o, 64);
    }
    float inv0 = 1.f / (den0 + 1e-16f);
    float inv1 = 1.f / (den1 + 1e-16f);
    // (2) combine relation numerators per-lane with the (now-uniform) inverses
    float4 accv;
    accv.x = num0.x * inv0 + num1.x * inv1;
    accv.y = num0.y * inv0 + num1.y * inv1;
    accv.z = num0.z * inv0 + num1.z * inv1;
    accv.w = num0.w * inv0 + num1.w * inv1;
    // (3) butterfly only the combined numerator: 8 shfls instead of 16
    #pragma unroll
    for (int o = 16; o <= 32; o <<= 1) {
        accv.x += __shfl_xor(accv.x, o, 64);
        accv.y += __shfl_xor(accv.y, o, 64);
        accv.z += __shfl_xor(accv.z, o, 64);
        accv.w += __shfl_xor(accv.w, o, 64);
    }

    if (g == 0) {
        const float is2 = 0.70710678118654752f;
        float o0 = 0.5f * accv.x * (1.f + erff(accv.x * is2));
        float o1 = 0.5f * accv.y * (1.f + erff(accv.y * is2));
        float o2 = 0.5f * accv.z * (1.f + erff(accv.z * is2));
        float o3 = 0.5f * accv.w * (1.f + erff(accv.w * is2));
        short h0,h1,h2,h3, l0,l1,l2,l3;
        cvt_pair(o0,h0,l0); cvt_pair(o1,h1,l1);
        cvt_pair(o2,h2,l2); cvt_pair(o3,h3,l3);
        long oo = (long)d * 128 + h * 64 + l * 4;
        *(shortx4*)(ohi + oo) = (shortx4){h0,h1,h2,h3};
        *(shortx4*)(olo + oo) = (shortx4){l0,l1,l2,l3};
    }
}

// ============ f32 vector GEMM kept for tiny MLP ============
#define BM 64
#define BN 64
#define BK 16
__global__ __launch_bounds__(256) void gemm_bias_kernel(
    const float* __restrict__ A, int lda,
    const float* __restrict__ B, int ldb,
    const float* __restrict__ bias,
    float* __restrict__ C, int ldc,
    int M, int K, int epilogue)
{
    __shared__ float As[BK][BM + 4];
    __shared__ float Bs[BK][BN + 4];
    const int t = threadIdx.x;
    const int row0 = blockIdx.y * BM;
    const int col0 = blockIdx.x * BN;
    const int tm = (t >> 4) << 2;
    const int tn = (t & 15) << 2;
    float acc[4][4] = {};
    for (int k0 = 0; k0 < K; k0 += BK) {
        #pragma unroll
        for (int i = 0; i < 4; ++i) {
            int idx = t + i * 256;
            int m = idx >> 4, kk = idx & 15;
            int gm = row0 + m;
            As[kk][m] = (gm < M) ? A[(long)gm * lda + (k0 + kk)] : 0.f;
        }
        #pragma unroll
        for (int i = 0; i < 4; ++i) {
            int idx = t + i * 256;
            int kk = idx >> 6, n = idx & 63;
            Bs[kk][n] = B[(long)(k0 + kk) * ldb + (col0 + n)];
        }
        __syncthreads();
        #pragma unroll
        for (int kk = 0; kk < BK; ++kk) {
            float a[4], b[4];
            #pragma unroll
            for (int i = 0; i < 4; ++i) a[i] = As[kk][tm + i];
            #pragma unroll
            for (int j = 0; j < 4; ++j) b[j] = Bs[kk][tn + j];
            #pragma unroll
            for (int i = 0; i < 4; ++i)
                #pragma unroll
                for (int j = 0; j < 4; ++j)
                    acc[i][j] = fmaf(a[i], b[j], acc[i][j]);
        }
        __syncthreads();
    }
    #pragma unroll
    for (int i = 0; i < 4; ++i) {
        int gm = row0 + tm + i;
        if (gm >= M) continue;
        #pragma unroll
        for (int j = 0; j < 4; ++j) {
            int gn = col0 + tn + j;
            float v = acc[i][j];
            if (bias) v += bias[gn];
            if (epilogue >= 1) v = fmaxf(v, 0.f);
            C[(long)gm * ldc + gn] = v;
        }
    }
}

// ============ pooling (reads bf16 hi/lo planes) ============
__device__ inline int lower_bound_i(const int* __restrict__ a, int n, int v)
{
    int lo = 0, hi = n;
    while (lo < hi) { int mid = (lo + hi) >> 1; if (a[mid] < v) lo = mid + 1; else hi = mid; }
    return lo;
}

__global__ void pool_kernel(const short* __restrict__ hhi, const short* __restrict__ hlo,
                            const int* __restrict__ batch,
                            float* __restrict__ s, int N)
{
    int g = blockIdx.x, part = blockIdx.y, c = threadIdx.x;
    int start = lower_bound_i(batch, N, g);
    int end = lower_bound_i(batch, N, g + 1);
    int cnt = end - start, parts = gridDim.y;
    int chunk = (cnt + parts - 1) / parts;
    int a = start + part * chunk;
    int b = a + chunk; if (b > end) b = end;
    if (a >= b) return;
    float sum = 0.f;
    for (int n = a; n < b; ++n) {
        long o = (long)n * HDIM + c;
        sum += b2f(hhi[o]) + b2f(hlo[o]);
    }
    atomicAdd(&s[g * HDIM + c], sum);
}

__global__ void pool_finalize(const float* __restrict__ s, const int* __restrict__ batch,
                              float* __restrict__ g_out, int N)
{
    int g = blockIdx.x, c = threadIdx.x;
    int start = lower_bound_i(batch, N, g);
    int end = lower_bound_i(batch, N, g + 1);
    float cnt = (float)((end - start) > 1 ? (end - start) : 1);
    g_out[g * HDIM + c] = s[g * HDIM + c] / cnt;
}

// ============ host ============
extern "C" void kernel_launch(void* const* d_in, const int* in_sizes, int n_in,
                              void* d_out, int out_size, void* d_ws, size_t ws_size,
                              hipStream_t stream)
{
    const float* x      = (const float*)d_in[0];
    const int*   e0     = (const int*)d_in[1];
    const int*   e1     = (const int*)d_in[2];
    const int*   batch  = (const int*)d_in[3];
    const float* W_k1   = (const float*)d_in[4];
    const float* W_q1   = (const float*)d_in[5];
    const float* W_v1   = (const float*)d_in[6];
    const float* a_rel1 = (const float*)d_in[7];
    const float* m_rel1 = (const float*)d_in[8];
    const float* W_a1   = (const float*)d_in[9];
    const float* W_k23  = (const float*)d_in[10];
    const float* W_q23  = (const float*)d_in[11];
    const float* W_v23  = (const float*)d_in[12];
    const float* a_rel23= (const float*)d_in[13];
    const float* m_rel23= (const float*)d_in[14];
    const float* W_a23  = (const float*)d_in[15];
    const float* W_m1   = (const float*)d_in[16];
    const float* W_m2   = (const float*)d_in[17];
    const float* b_k1   = (const float*)d_in[18];
    const float* b_q1   = (const float*)d_in[19];
    const float* b_v1   = (const float*)d_in[20];
    const float* b_a1   = (const float*)d_in[21];
    const float* b_k23  = (const float*)d_in[22];
    const float* b_q23  = (const float*)d_in[23];
    const float* b_v23  = (const float*)d_in[24];
    const float* b_a23  = (const float*)d_in[25];
    const float* skip23 = (const float*)d_in[26];
    const float* b_m1   = (const float*)d_in[27];
    const float* b_m2   = (const float*)d_in[28];
    const float* p_rel1 = (const float*)d_in[29];
    const float* p_rel23= (const float*)d_in[30];

    const int N = N_NODES_C;
    const int E = in_sizes[1] / 2;
    const int F = in_sizes[0] / N;            // 512
    const long NP = (long)N * HDIM;           // 6.4M plane elements

    // ---- workspace layout ----
    float* ws    = (float*)d_ws;
    float* QKV   = ws;                                  // N*640 f32 (128 MB)
    short* ACChi = (short*)(QKV + (long)N * 640);       // 6 planes, 12.8 MB each
    short* ACClo = ACChi + NP;
    short* H1hi  = ACClo + NP;
    short* H1lo  = H1hi + NP;
    short* H2hi  = H1lo + NP;
    short* H2lo  = H2hi + NP;
    short* WThi  = H2lo + NP;                           // 640*512 max
    short* WTlo  = WThi + 640 * 512;
    short* WaThi = WTlo + 640 * 512;                    // 128*128
    short* WaTlo = WaThi + 128 * 128;
    float* B640  = (float*)(WaTlo + 128 * 128);         // 640
    float* S     = B640 + 640;
    float* GM    = S + N_GRAPHS_C * HDIM;
    float* M1    = GM + N_GRAPHS_C * HDIM;
    int*   off0  = (int*)(M1 + N_GRAPHS_C * HDIM);      // N+1
    int*   ss0   = off0 + (N + 1);                      // E
    int*   off1  = ss0 + E;                             // N+1
    int*   ss1   = off1 + (N + 1);                      // E
    int*   counts = (int*)QKV;                          // 2N, alias: dead before QKV written
    int*   cursor = counts + 2 * N;                     // 2N
    size_t needed = (size_t)((char*)(ss1 + E) - (char*)d_ws);
    if (ws_size < needed) return;

    // ---- build CSR once, both relations per launch ----
    {
        int eb = (E + 255) / 256;
        hipMemsetAsync(counts, 0, (size_t)(2 * N) * sizeof(int), stream);
        dim3 cg(eb, 2);
        csr_count2<<<cg, 256, 0, stream>>>(e0, e1, counts, E, N);
        csr_scan2<<<2, 1024, 0, stream>>>(counts, off0, off1, cursor, N, E);
        csr_fill2<<<cg, 256, 0, stream>>>(e0, e1, cursor, ss0, ss1, E, N);
    }

    const int nrb = (N + GBM - 1) / GBM;   // 391 row blocks

    auto run_layer = [&](const void* Ain, const short* AinLo, int AF, int Fin,
                         const float* Wk, const float* bk,
                         const float* Wq, const float* bq,
                         const float* Wv, const float* bv,
                         const float* arel, const float* mrel, const float* prel,
                         const float* Wa, const float* ba,
                         const float* gate, const short* skipHi, const short* skipLo,
                         short* outHi, short* outLo) {
        dim3 bg((Fin + 255) / 256, 640);
        build_wbigT_p<<<bg, 256, 0, stream>>>(Wq, bq, Wk, bk, Wv, bv,
                                              arel, mrel, WThi, WTlo, B640, Fin);
        int qb = (640 / GBN) * nrb;        // 1D grid, XCD-swizzled in-kernel
        if (AF)
            gemm_planes<1><<<qb, 256, 0, stream>>>(Ain, nullptr, Fin, WThi, WTlo, Fin,
                B640, QKV, nullptr, nullptr, N, 640, Fin, 0, nullptr, nullptr, nullptr);
        else
            gemm_planes<0><<<qb, 256, 0, stream>>>(Ain, AinLo, Fin, WThi, WTlo, Fin,
                B640, QKV, nullptr, nullptr, N, 640, Fin, 0, nullptr, nullptr, nullptr);

        node_attn_kernel<<<(N * 2 + 3) / 4, 256, 0, stream>>>(
            QKV, off0, ss0, off1, ss1, prel, ACChi, ACClo, N);

        transpose128p<<<64, 256, 0, stream>>>(Wa, WaThi, WaTlo);
        gemm_planes<0><<<nrb, 256, 0, stream>>>(ACChi, ACClo, 128, WaThi, WaTlo, 128,
            ba, nullptr, outHi, outLo, N, 128, 128,
            gate ? 3 : 2, gate, skipHi, skipLo);
    };

    // layer 1 (f32 x input, no skip) -> H1 planes
    run_layer(x, nullptr, 1, F, W_k1, b_k1, W_q1, b_q1, W_v1, b_v1,
              a_rel1, m_rel1, p_rel1, W_a1, b_a1,
              nullptr, nullptr, nullptr, H1hi, H1lo);
    // layer 2 (H1 planes, gated skip from H1) -> H2 planes
    run_layer(H1hi, H1lo, 0, HDIM, W_k23, b_k23, W_q23, b_q23, W_v23, b_v23,
              a_rel23, m_rel23, p_rel23, W_a23, b_a23,
              skip23, H1hi, H1lo, H2hi, H2lo);
    // layer 3 (H2 planes, gated skip from H2) -> H1 planes (reuse)
    run_layer(H2hi, H2lo, 0, HDIM, W_k23 + 16384, b_k23 + 128, W_q23 + 16384, b_q23 + 128,
              W_v23 + 16384, b_v23 + 128, a_rel23 + 16384, m_rel23 + 16384,
              p_rel23 + 4, W_a23 + 16384, b_a23 + 128,
              skip23 + 1, H2hi, H2lo, H1hi, H1lo);

    // global mean pool (batch sorted)
    hipMemsetAsync(S, 0, (size_t)N_GRAPHS_C * HDIM * sizeof(float), stream);
    dim3 pg(N_GRAPHS_C, 8);
    pool_kernel<<<pg, HDIM, 0, stream>>>(H1hi, H1lo, batch, S, N);
    pool_finalize<<<N_GRAPHS_C, HDIM, 0, stream>>>(S, batch, GM, N);

    // MLP
    {
        dim3 g1(128 / BN, 1);
        gemm_bias_kernel<<<g1, 256, 0, stream>>>(GM, 128, W_m1, 128, b_m1, M1, 128,
                                                 N_GRAPHS_C, 128, 1);
        dim3 g2(256 / BN, 1);
        gemm_bias_kernel<<<g2, 256, 0, stream>>>(M1, 128, W_m2, 256, b_m2,
                                                 (float*)d_out, 256, N_GRAPHS_C, 128, 0);
    }
}

// Round 5
// 982.976 us; speedup vs baseline: 1.2561x; 1.0296x over previous
//
#include <hip/hip_runtime.h>
#include <math.h>

#define N_NODES_C 50000
#define N_GRAPHS_C 64
#define HDIM 128

typedef short bf16x8 __attribute__((ext_vector_type(8)));
typedef short shortx4 __attribute__((ext_vector_type(4)));
typedef float floatx4 __attribute__((ext_vector_type(4)));

// split f32 -> hi (truncated bf16) + lo (bf16 of exact residual)
__device__ __forceinline__ void cvt_pair(float x, short& h, short& l) {
    union { float f; unsigned u; } a; a.f = x;
    h = (short)(a.u >> 16);
    union { unsigned u; float f; } b; b.u = a.u & 0xFFFF0000u;
    union { float f; unsigned u; } c; c.f = x - b.f;   // exact residual
    l = (short)(c.u >> 16);
}

__device__ __forceinline__ float b2f(short s) {
    union { unsigned u; float f; } x; x.u = ((unsigned)(unsigned short)s) << 16;
    return x.f;
}

// async global->LDS copy, 16 B per lane, LDS dest = wave-uniform base + lane*16
__device__ __forceinline__ void gld_lds16(const void* gsrc, void* ldst) {
    __builtin_amdgcn_global_load_lds(
        (const __attribute__((address_space(1))) unsigned int*)gsrc,
        (__attribute__((address_space(3))) unsigned int*)ldst,
        16, 0, 0);
}

// ============ MFMA GEMM with global_load_lds staging ============
// R5: R0 single-buffer schedule (32 KB LDS: stage -> sync -> compute -> sync)
// + __launch_bounds__(256,3): 168 total regs fit 3 waves/SIMD (512/168=3.05)
// and 32 KB LDS fits 5 blocks/CU -> occupancy 2->3 blocks/CU. Explicit dbuf
// measured 0 gain at equal occupancy (R0==R1); occupancy is the lever.
// + bf16-granule XOR swizzle (source+read sides) halves LDS bank conflicts
// (proven in R2: 8.0M->4.0M; R2's regression was its schedule, not this).
// C[M,N] = A[M,K] @ BT[N,K]^T (+bias). A: f32 (AF32=1) or bf16 hi/lo planes.
// B: always bf16 hi/lo planes. Split-bf16 3-MFMA for f32-class accuracy.
// mode 0: Cf32 = v + bias          (ldc = Ntot)
// mode 2: planes = relu(v + bias)  (ldc = 128)
// mode 3: planes = relu(gate*v+bias' + (1-gate)*prev)  (ldc = 128)
#define GBM 128
#define GBN 128
#define GBK 32

template<int AF32>
__global__ __launch_bounds__(256, 3) void gemm_planes(
    const void* __restrict__ Aptr, const short* __restrict__ Alo, int lda,
    const short* __restrict__ Bhi, const short* __restrict__ Blo, int ldbt,
    const float* __restrict__ bias,
    float* __restrict__ Cf, short* __restrict__ Chi, short* __restrict__ Clo,
    int M, int Ntot, int K,
    int mode, const float* __restrict__ skipGate,
    const short* __restrict__ Phi, const short* __restrict__ Plo)
{
    constexpr int ASZ = AF32 ? (GBM * GBK * 2) : (GBM * GBK);  // shorts
    constexpr int BSZ = GBN * GBK;
    __shared__ __align__(16) short AsH[ASZ];
    __shared__ __align__(16) short AsL[AF32 ? 8 : (GBM * GBK)];
    __shared__ __align__(16) short BsH[BSZ];
    __shared__ __align__(16) short BsL[BSZ];

    const int t = threadIdx.x;
    const int lane = t & 63;
    const int wave = t >> 6;
    const int wm = wave & 1, wn = wave >> 1;
    const int quad = lane >> 4, l15 = lane & 15;

    // XCD-bijective chunked swizzle (valid for any nwg), column-fastest decode
    const int nwg = gridDim.x, bid0 = blockIdx.x;
    const int qq = nwg >> 3, rr = nwg & 7;
    const int xcd = bid0 & 7, idx = bid0 >> 3;
    const int swz = (xcd < rr ? xcd * (qq + 1)
                              : rr * (qq + 1) + (xcd - rr) * qq) + idx;
    const int ncb = (Ntot + GBN - 1) / GBN;
    const long row0 = (long)(swz / ncb) * GBM;
    const long col0 = (long)(swz % ncb) * GBN;

    floatx4 acc[4][4];
    #pragma unroll
    for (int i = 0; i < 4; ++i)
        #pragma unroll
        for (int j = 0; j < 4; ++j)
            acc[i][j] = (floatx4){0.f, 0.f, 0.f, 0.f};

    for (int k0 = 0; k0 < K; k0 += GBK) {
        if (AF32) {
            // f32 tile 128x32 = 16 KB, 16 chunks of 1 KB (8 rows each),
            // kc8^r8 granule swizzle: fragment reads ~conflict-free
            const float* Af = (const float*)Aptr;
            int r8 = lane >> 3, kc8 = lane & 7;
            #pragma unroll
            for (int cc = 0; cc < 4; ++cc) {
                int ch = wave * 4 + cc;
                long gr = row0 + ch * 8 + r8;
                if (gr > M - 1) gr = M - 1;
                gld_lds16(Af + gr * lda + k0 + ((kc8 ^ r8) << 2),
                          (short*)AsH + ch * 512);
            }
        } else {
            const short* Ahi = (const short*)Aptr;
            int r16 = lane >> 2, g4 = lane & 3;
            int gs = (g4 ^ ((r16 >> 1) & 3)) * 8;   // granule swizzle (src side)
            #pragma unroll
            for (int cc = 0; cc < 2; ++cc) {
                int ch = wave * 2 + cc;
                long gr = row0 + ch * 16 + r16;
                if (gr > M - 1) gr = M - 1;
                long go = gr * lda + k0 + gs;
                gld_lds16(Ahi + go, AsH + ch * 512);
                gld_lds16(Alo + go, AsL + ch * 512);
            }
        }
        {
            int r16 = lane >> 2, g4 = lane & 3;
            int gs = (g4 ^ ((r16 >> 1) & 3)) * 8;   // granule swizzle (src side)
            #pragma unroll
            for (int cc = 0; cc < 2; ++cc) {
                int ch = wave * 2 + cc;
                long gc = col0 + ch * 16 + r16;
                if (gc > Ntot - 1) gc = Ntot - 1;
                long go = gc * ldbt + k0 + gs;
                gld_lds16(Bhi + go, BsH + ch * 512);
                gld_lds16(Blo + go, BsL + ch * 512);
            }
        }
        __syncthreads();   // compiler inserts vmcnt wait for global_load_lds

        bf16x8 aH[4], aL[4], bH[4], bL[4];
        if (AF32) {
            #pragma unroll
            for (int i = 0; i < 4; ++i) {
                int row = wm * 64 + i * 16 + l15;
                const float* fr = (const float*)AsH + row * 32;
                int x7 = row & 7;
                float4 f0 = *(const float4*)(fr + (((quad * 2)     ^ x7) << 2));
                float4 f1 = *(const float4*)(fr + (((quad * 2 + 1) ^ x7) << 2));
                short h0,h1,h2,h3,h4,h5,h6,h7, l0,l1,l2,l3,l4,l5,l6,l7;
                cvt_pair(f0.x,h0,l0); cvt_pair(f0.y,h1,l1);
                cvt_pair(f0.z,h2,l2); cvt_pair(f0.w,h3,l3);
                cvt_pair(f1.x,h4,l4); cvt_pair(f1.y,h5,l5);
                cvt_pair(f1.z,h6,l6); cvt_pair(f1.w,h7,l7);
                aH[i] = (bf16x8){h0,h1,h2,h3,h4,h5,h6,h7};
                aL[i] = (bf16x8){l0,l1,l2,l3,l4,l5,l6,l7};
            }
        } else {
            #pragma unroll
            for (int i = 0; i < 4; ++i) {
                int row = wm * 64 + i * 16 + l15;
                int off = row * 32 + ((quad ^ ((row >> 1) & 3)) * 8);
                aH[i] = *(const bf16x8*)&AsH[off];
                aL[i] = *(const bf16x8*)&AsL[off];
            }
        }
        #pragma unroll
        for (int j = 0; j < 4; ++j) {
            int row = wn * 64 + j * 16 + l15;
            int off = row * 32 + ((quad ^ ((row >> 1) & 3)) * 8);
            bH[j] = *(const bf16x8*)&BsH[off];
            bL[j] = *(const bf16x8*)&BsL[off];
        }
        #pragma unroll
        for (int i = 0; i < 4; ++i)
            #pragma unroll
            for (int j = 0; j < 4; ++j) {
                acc[i][j] = __builtin_amdgcn_mfma_f32_16x16x32_bf16(aH[i], bH[j], acc[i][j], 0, 0, 0);
                acc[i][j] = __builtin_amdgcn_mfma_f32_16x16x32_bf16(aH[i], bL[j], acc[i][j], 0, 0, 0);
                acc[i][j] = __builtin_amdgcn_mfma_f32_16x16x32_bf16(aL[i], bH[j], acc[i][j], 0, 0, 0);
            }
        __syncthreads();
    }

    float gate = 0.f;
    if (mode == 3) gate = 1.f / (1.f + __expf(-skipGate[0]));

    #pragma unroll
    for (int i = 0; i < 4; ++i) {
        #pragma unroll
        for (int r4 = 0; r4 < 4; ++r4) {
            long grow = row0 + wm * 64 + i * 16 + quad * 4 + r4;
            if (grow >= M) continue;
            #pragma unroll
            for (int j = 0; j < 4; ++j) {
                long gcol = col0 + wn * 64 + j * 16 + l15;
                if (gcol >= Ntot) continue;
                float v = acc[i][j][r4];
                if (bias) v += bias[gcol];
                if (mode == 0) {
                    Cf[grow * Ntot + gcol] = v;
                } else {
                    if (mode == 3) {
                        long po = grow * 128 + gcol;
                        float pv = b2f(Phi[po]) + b2f(Plo[po]);
                        v = gate * v + (1.f - gate) * pv;
                    }
                    v = fmaxf(v, 0.f);
                    short hh, ll; cvt_pair(v, hh, ll);
                    Chi[grow * 128 + gcol] = hh;
                    Clo[grow * 128 + gcol] = ll;
                }
            }
        }
    }
}

// ============ build fused WbigT[640, F] as bf16 hi/lo planes + bias640 ============
// cols: [0,128) q | [128,384) k_r | [384,640) v_r ; one c per blockIdx.y
__global__ __launch_bounds__(256) void build_wbigT_p(
    const float* __restrict__ Wq, const float* __restrict__ bq,
    const float* __restrict__ Wk, const float* __restrict__ bk,
    const float* __restrict__ Wv, const float* __restrict__ bv,
    const float* __restrict__ arel, const float* __restrict__ mrel,
    short* __restrict__ WThi, short* __restrict__ WTlo,
    float* __restrict__ bias, int F)
{
    __shared__ float Trow[64];
    int c = blockIdx.y;
    int f = blockIdx.x * 256 + threadIdx.x;
    float w = 0.f, b = 0.f;
    if (c < 128) {
        if (f < F) w = Wq[(long)f * 128 + c];
        b = bq[c];
    } else {
        int cc = c - 128;
        const float* Wsrc; const float* bsrc; const float* T;
        if (cc < 256) { Wsrc = Wk; bsrc = bk; T = arel; }
        else { cc -= 256; Wsrc = Wv; bsrc = bv; T = mrel; }
        int r = cc >> 7, j = cc & 127, h = j >> 6, e = j & 63;
        const float* Tr = T + (long)(r * 2 + h) * 4096 + e;
        if (threadIdx.x < 64) Trow[threadIdx.x] = Tr[(long)threadIdx.x * 64];
        __syncthreads();
        if (f < F) {
            const float* Wrow = Wsrc + (long)f * 128 + h * 64;
            float s = 0.f;
            #pragma unroll 4
            for (int d = 0; d < 64; ++d) s = fmaf(Wrow[d], Trow[d], s);
            w = s;
        }
        if (f == 0) {
            const float* brow = bsrc + h * 64;
            float sb = 0.f;
            for (int d = 0; d < 64; ++d) sb = fmaf(brow[d], Trow[d], sb);
            b = sb;
        }
    }
    if (f < F) {
        short hh, ll; cvt_pair(w, hh, ll);
        WThi[(long)c * F + f] = hh;
        WTlo[(long)c * F + f] = ll;
    }
    if (f == 0) bias[c] = b;
}

// W[128,128] -> WT planes [128,128] bf16 hi/lo
__global__ void transpose128p(const float* __restrict__ W,
                              short* __restrict__ hi, short* __restrict__ lo)
{
    int idx = blockIdx.x * 256 + threadIdx.x;   // 16384
    int c = idx >> 7, f = idx & 127;
    short hh, ll; cvt_pair(W[f * 128 + c], hh, ll);
    hi[idx] = hh; lo[idx] = ll;
}

// ============ CSR build, both relations per launch (blockIdx.y = r) ============
__global__ void csr_count2(const int* __restrict__ e0p, const int* __restrict__ e1p,
                           int* __restrict__ counts, int E, int N)
{
    int e = blockIdx.x * 256 + threadIdx.x;
    int r = blockIdx.y;
    const int* dst = (r ? e1p : e0p) + E;
    if (e < E) atomicAdd(&counts[r * N + dst[e]], 1);
}

__global__ __launch_bounds__(1024) void csr_scan2(
    const int* __restrict__ counts,
    int* __restrict__ off0, int* __restrict__ off1,
    int* __restrict__ cursor, int N, int E)
{
    __shared__ int part[1024];
    int r = blockIdx.x;
    const int* cnt = counts + (long)r * N;
    int* offs = r ? off1 : off0;
    int* cur  = cursor + (long)r * N;
    int t = threadIdx.x;
    int chunk = (N + 1023) / 1024;
    int a = t * chunk, b = a + chunk; if (b > N) b = N;
    int s = 0;
    for (int i = a; i < b; ++i) s += cnt[i];
    part[t] = s;
    __syncthreads();
    for (int off = 1; off < 1024; off <<= 1) {
        int v = (t >= off) ? part[t - off] : 0;
        __syncthreads();
        if (t >= off) part[t] += v;
        __syncthreads();
    }
    int p = (t == 0) ? 0 : part[t - 1];
    for (int i = a; i < b; ++i) {
        offs[i] = p; cur[i] = p; p += cnt[i];
    }
    if (t == 1023) offs[N] = E;
}

__global__ void csr_fill2(const int* __restrict__ e0p, const int* __restrict__ e1p,
                          int* __restrict__ cursor,
                          int* __restrict__ ss0, int* __restrict__ ss1, int E, int N)
{
    int e = blockIdx.x * 256 + threadIdx.x;
    if (e >= E) return;
    int r = blockIdx.y;
    const int* ed = r ? e1p : e0p;
    int* ss = r ? ss1 : ss0;
    int pos = atomicAdd(&cursor[r * N + ed[E + e]], 1);
    ss[pos] = ed[e];
}

// ============ node attention: one wave per (node, head) ============
// 16 lanes per edge, float4 gathers, BOTH relations interleaved in one loop.
// Epilogue: den-first reduction (12 shfls vs 20, R4).
__global__ __launch_bounds__(256) void node_attn_kernel(
    const float* __restrict__ qkv,
    const int* __restrict__ off0, const int* __restrict__ ss0,
    const int* __restrict__ off1, const int* __restrict__ ss1,
    const float* __restrict__ prel,     // [2][2] (r,h)
    short* __restrict__ ohi, short* __restrict__ olo, int N)
{
    int wid = blockIdx.x * 4 + (threadIdx.x >> 6);
    int lane = threadIdx.x & 63;
    int d = wid >> 1, h = wid & 1;
    if (d >= N) return;
    int g = lane >> 4, l = lane & 15;

    float4 q4 = *(const float4*)(qkv + (long)d * 640 + h * 64 + l * 4);

    int c0 = off0[d], b0 = off0[d + 1];
    int c1 = off1[d], b1 = off1[d + 1];
    const float* kp0 = qkv + 128 + h * 64 + l * 4;
    const float* vp0 = qkv + 384 + h * 64 + l * 4;
    const float* kp1 = kp0 + 128;
    const float* vp1 = vp0 + 128;
    float pr0 = prel[h] * 0.125f;       // includes 1/sqrt(64)
    float pr1 = prel[2 + h] * 0.125f;

    const float4 fz = {0.f, 0.f, 0.f, 0.f};
    float4 num0 = fz, num1 = fz;
    float den0 = 0.f, den1 = 0.f;

    while (c0 < b0 || c1 < b1) {
        // issue all gathers for both relations first (overlapped latency)
        float4 k0 = fz, v0 = fz, k1 = fz, v1 = fz;
        bool a0 = (c0 < b0) && (c0 + g < b0);
        bool a1 = (c1 < b1) && (c1 + g < b1);
        if (a0) {
            long so = (long)ss0[c0 + g] * 640;
            k0 = *(const float4*)(kp0 + so);
            v0 = *(const float4*)(vp0 + so);
        }
        if (a1) {
            long so = (long)ss1[c1 + g] * 640;
            k1 = *(const float4*)(kp1 + so);
            v1 = *(const float4*)(vp1 + so);
        }
        if (c0 < b0) {
            float p = q4.x*k0.x + q4.y*k0.y + q4.z*k0.z + q4.w*k0.w;
            p += __shfl_xor(p, 1, 16);
            p += __shfl_xor(p, 2, 16);
            p += __shfl_xor(p, 4, 16);
            p += __shfl_xor(p, 8, 16);
            float w = a0 ? __expf(p * pr0) : 0.f;
            den0 += w;
            num0.x = fmaf(w, v0.x, num0.x);
            num0.y = fmaf(w, v0.y, num0.y);
            num0.z = fmaf(w, v0.z, num0.z);
            num0.w = fmaf(w, v0.w, num0.w);
            c0 += 4;
        }
        if (c1 < b1) {
            float p = q4.x*k1.x + q4.y*k1.y + q4.z*k1.z + q4.w*k1.w;
            p += __shfl_xor(p, 1, 16);
            p += __shfl_xor(p, 2, 16);
            p += __shfl_xor(p, 4, 16);
            p += __shfl_xor(p, 8, 16);
            float w = a1 ? __expf(p * pr1) : 0.f;
            den1 += w;
            num1.x = fmaf(w, v1.x, num1.x);
            num1.y = fmaf(w, v1.y, num1.y);
            num1.z = fmaf(w, v1.z, num1.z);
            num1.w = fmaf(w, v1.w, num1.w);
            c1 += 4;
        }
    }

    // (1) reduce denominators across the 4 edge groups
    #pragma unroll
    for (int o = 16; o <= 32; o <<= 1) {
        den0 += __shfl_xor(den0, o, 64);
        den1 += __shfl_xor(den1, o, 64);
    }
    float inv0 = 1.f / (den0 + 1e-16f);
    float inv1 = 1.f / (den1 + 1e-16f);
    // (2) combine relation numerators per-lane with the uniform inverses
    float4 accv;
    accv.x = num0.x * inv0 + num1.x * inv1;
    accv.y = num0.y * inv0 + num1.y * inv1;
    accv.z = num0.z * inv0 + num1.z * inv1;
    accv.w = num0.w * inv0 + num1.w * inv1;
    // (3) butterfly only the combined numerator
    #pragma unroll
    for (int o = 16; o <= 32; o <<= 1) {
        accv.x += __shfl_xor(accv.x, o, 64);
        accv.y += __shfl_xor(accv.y, o, 64);
        accv.z += __shfl_xor(accv.z, o, 64);
        accv.w += __shfl_xor(accv.w, o, 64);
    }

    if (g == 0) {
        const float is2 = 0.70710678118654752f;
        float o0 = 0.5f * accv.x * (1.f + erff(accv.x * is2));
        float o1 = 0.5f * accv.y * (1.f + erff(accv.y * is2));
        float o2 = 0.5f * accv.z * (1.f + erff(accv.z * is2));
        float o3 = 0.5f * accv.w * (1.f + erff(accv.w * is2));
        short h0,h1,h2,h3, l0,l1,l2,l3;
        cvt_pair(o0,h0,l0); cvt_pair(o1,h1,l1);
        cvt_pair(o2,h2,l2); cvt_pair(o3,h3,l3);
        long oo = (long)d * 128 + h * 64 + l * 4;
        *(shortx4*)(ohi + oo) = (shortx4){h0,h1,h2,h3};
        *(shortx4*)(olo + oo) = (shortx4){l0,l1,l2,l3};
    }
}

// ============ f32 vector GEMM kept for tiny MLP ============
#define BM 64
#define BN 64
#define BK 16
__global__ __launch_bounds__(256) void gemm_bias_kernel(
    const float* __restrict__ A, int lda,
    const float* __restrict__ B, int ldb,
    const float* __restrict__ bias,
    float* __restrict__ C, int ldc,
    int M, int K, int epilogue)
{
    __shared__ float As[BK][BM + 4];
    __shared__ float Bs[BK][BN + 4];
    const int t = threadIdx.x;
    const int row0 = blockIdx.y * BM;
    const int col0 = blockIdx.x * BN;
    const int tm = (t >> 4) << 2;
    const int tn = (t & 15) << 2;
    float acc[4][4] = {};
    for (int k0 = 0; k0 < K; k0 += BK) {
        #pragma unroll
        for (int i = 0; i < 4; ++i) {
            int idx = t + i * 256;
            int m = idx >> 4, kk = idx & 15;
            int gm = row0 + m;
            As[kk][m] = (gm < M) ? A[(long)gm * lda + (k0 + kk)] : 0.f;
        }
        #pragma unroll
        for (int i = 0; i < 4; ++i) {
            int idx = t + i * 256;
            int kk = idx >> 6, n = idx & 63;
            Bs[kk][n] = B[(long)(k0 + kk) * ldb + (col0 + n)];
        }
        __syncthreads();
        #pragma unroll
        for (int kk = 0; kk < BK; ++kk) {
            float a[4], b[4];
            #pragma unroll
            for (int i = 0; i < 4; ++i) a[i] = As[kk][tm + i];
            #pragma unroll
            for (int j = 0; j < 4; ++j) b[j] = Bs[kk][tn + j];
            #pragma unroll
            for (int i = 0; i < 4; ++i)
                #pragma unroll
                for (int j = 0; j < 4; ++j)
                    acc[i][j] = fmaf(a[i], b[j], acc[i][j]);
        }
        __syncthreads();
    }
    #pragma unroll
    for (int i = 0; i < 4; ++i) {
        int gm = row0 + tm + i;
        if (gm >= M) continue;
        #pragma unroll
        for (int j = 0; j < 4; ++j) {
            int gn = col0 + tn + j;
            float v = acc[i][j];
            if (bias) v += bias[gn];
            if (epilogue >= 1) v = fmaxf(v, 0.f);
            C[(long)gm * ldc + gn] = v;
        }
    }
}

// ============ pooling (reads bf16 hi/lo planes) ============
__device__ inline int lower_bound_i(const int* __restrict__ a, int n, int v)
{
    int lo = 0, hi = n;
    while (lo < hi) { int mid = (lo + hi) >> 1; if (a[mid] < v) lo = mid + 1; else hi = mid; }
    return lo;
}

__global__ void pool_kernel(const short* __restrict__ hhi, const short* __restrict__ hlo,
                            const int* __restrict__ batch,
                            float* __restrict__ s, int N)
{
    int g = blockIdx.x, part = blockIdx.y, c = threadIdx.x;
    int start = lower_bound_i(batch, N, g);
    int end = lower_bound_i(batch, N, g + 1);
    int cnt = end - start, parts = gridDim.y;
    int chunk = (cnt + parts - 1) / parts;
    int a = start + part * chunk;
    int b = a + chunk; if (b > end) b = end;
    if (a >= b) return;
    float sum = 0.f;
    for (int n = a; n < b; ++n) {
        long o = (long)n * HDIM + c;
        sum += b2f(hhi[o]) + b2f(hlo[o]);
    }
    atomicAdd(&s[g * HDIM + c], sum);
}

__global__ void pool_finalize(const float* __restrict__ s, const int* __restrict__ batch,
                              float* __restrict__ g_out, int N)
{
    int g = blockIdx.x, c = threadIdx.x;
    int start = lower_bound_i(batch, N, g);
    int end = lower_bound_i(batch, N, g + 1);
    float cnt = (float)((end - start) > 1 ? (end - start) : 1);
    g_out[g * HDIM + c] = s[g * HDIM + c] / cnt;
}

// ============ host ============
extern "C" void kernel_launch(void* const* d_in, const int* in_sizes, int n_in,
                              void* d_out, int out_size, void* d_ws, size_t ws_size,
                              hipStream_t stream)
{
    const float* x      = (const float*)d_in[0];
    const int*   e0     = (const int*)d_in[1];
    const int*   e1     = (const int*)d_in[2];
    const int*   batch  = (const int*)d_in[3];
    const float* W_k1   = (const float*)d_in[4];
    const float* W_q1   = (const float*)d_in[5];
    const float* W_v1   = (const float*)d_in[6];
    const float* a_rel1 = (const float*)d_in[7];
    const float* m_rel1 = (const float*)d_in[8];
    const float* W_a1   = (const float*)d_in[9];
    const float* W_k23  = (const float*)d_in[10];
    const float* W_q23  = (const float*)d_in[11];
    const float* W_v23  = (const float*)d_in[12];
    const float* a_rel23= (const float*)d_in[13];
    const float* m_rel23= (const float*)d_in[14];
    const float* W_a23  = (const float*)d_in[15];
    const float* W_m1   = (const float*)d_in[16];
    const float* W_m2   = (const float*)d_in[17];
    const float* b_k1   = (const float*)d_in[18];
    const float* b_q1   = (const float*)d_in[19];
    const float* b_v1   = (const float*)d_in[20];
    const float* b_a1   = (const float*)d_in[21];
    const float* b_k23  = (const float*)d_in[22];
    const float* b_q23  = (const float*)d_in[23];
    const float* b_v23  = (const float*)d_in[24];
    const float* b_a23  = (const float*)d_in[25];
    const float* skip23 = (const float*)d_in[26];
    const float* b_m1   = (const float*)d_in[27];
    const float* b_m2   = (const float*)d_in[28];
    const float* p_rel1 = (const float*)d_in[29];
    const float* p_rel23= (const float*)d_in[30];

    const int N = N_NODES_C;
    const int E = in_sizes[1] / 2;
    const int F = in_sizes[0] / N;            // 512
    const long NP = (long)N * HDIM;           // 6.4M plane elements

    // ---- workspace layout ----
    float* ws    = (float*)d_ws;
    float* QKV   = ws;                                  // N*640 f32 (128 MB)
    short* ACChi = (short*)(QKV + (long)N * 640);       // 6 planes, 12.8 MB each
    short* ACClo = ACChi + NP;
    short* H1hi  = ACClo + NP;
    short* H1lo  = H1hi + NP;
    short* H2hi  = H1lo + NP;
    short* H2lo  = H2hi + NP;
    short* WThi  = H2lo + NP;                           // 640*512 max
    short* WTlo  = WThi + 640 * 512;
    short* WaThi = WTlo + 640 * 512;                    // 128*128
    short* WaTlo = WaThi + 128 * 128;
    float* B640  = (float*)(WaTlo + 128 * 128);         // 640
    float* S     = B640 + 640;
    float* GM    = S + N_GRAPHS_C * HDIM;
    float* M1    = GM + N_GRAPHS_C * HDIM;
    int*   off0  = (int*)(M1 + N_GRAPHS_C * HDIM);      // N+1
    int*   ss0   = off0 + (N + 1);                      // E
    int*   off1  = ss0 + E;                             // N+1
    int*   ss1   = off1 + (N + 1);                      // E
    int*   counts = (int*)QKV;                          // 2N, alias: dead before QKV written
    int*   cursor = counts + 2 * N;                     // 2N
    size_t needed = (size_t)((char*)(ss1 + E) - (char*)d_ws);
    if (ws_size < needed) return;

    // ---- build CSR once, both relations per launch ----
    {
        int eb = (E + 255) / 256;
        hipMemsetAsync(counts, 0, (size_t)(2 * N) * sizeof(int), stream);
        dim3 cg(eb, 2);
        csr_count2<<<cg, 256, 0, stream>>>(e0, e1, counts, E, N);
        csr_scan2<<<2, 1024, 0, stream>>>(counts, off0, off1, cursor, N, E);
        csr_fill2<<<cg, 256, 0, stream>>>(e0, e1, cursor, ss0, ss1, E, N);
    }

    const int nrb = (N + GBM - 1) / GBM;   // 391 row blocks

    auto run_layer = [&](const void* Ain, const short* AinLo, int AF, int Fin,
                         const float* Wk, const float* bk,
                         const float* Wq, const float* bq,
                         const float* Wv, const float* bv,
                         const float* arel, const float* mrel, const float* prel,
                         const float* Wa, const float* ba,
                         const float* gate, const short* skipHi, const short* skipLo,
                         short* outHi, short* outLo) {
        dim3 bg((Fin + 255) / 256, 640);
        build_wbigT_p<<<bg, 256, 0, stream>>>(Wq, bq, Wk, bk, Wv, bv,
                                              arel, mrel, WThi, WTlo, B640, Fin);
        int qb = (640 / GBN) * nrb;        // 1D grid, XCD-swizzled in-kernel
        if (AF)
            gemm_planes<1><<<qb, 256, 0, stream>>>(Ain, nullptr, Fin, WThi, WTlo, Fin,
                B640, QKV, nullptr, nullptr, N, 640, Fin, 0, nullptr, nullptr, nullptr);
        else
            gemm_planes<0><<<qb, 256, 0, stream>>>(Ain, AinLo, Fin, WThi, WTlo, Fin,
                B640, QKV, nullptr, nullptr, N, 640, Fin, 0, nullptr, nullptr, nullptr);

        node_attn_kernel<<<(N * 2 + 3) / 4, 256, 0, stream>>>(
            QKV, off0, ss0, off1, ss1, prel, ACChi, ACClo, N);

        transpose128p<<<64, 256, 0, stream>>>(Wa, WaThi, WaTlo);
        gemm_planes<0><<<nrb, 256, 0, stream>>>(ACChi, ACClo, 128, WaThi, WaTlo, 128,
            ba, nullptr, outHi, outLo, N, 128, 128,
            gate ? 3 : 2, gate, skipHi, skipLo);
    };

    // layer 1 (f32 x input, no skip) -> H1 planes
    run_layer(x, nullptr, 1, F, W_k1, b_k1, W_q1, b_q1, W_v1, b_v1,
              a_rel1, m_rel1, p_rel1, W_a1, b_a1,
              nullptr, nullptr, nullptr, H1hi, H1lo);
    // layer 2 (H1 planes, gated skip from H1) -> H2 planes
    run_layer(H1hi, H1lo, 0, HDIM, W_k23, b_k23, W_q23, b_q23, W_v23, b_v23,
              a_rel23, m_rel23, p_rel23, W_a23, b_a23,
              skip23, H1hi, H1lo, H2hi, H2lo);
    // layer 3 (H2 planes, gated skip from H2) -> H1 planes (reuse)
    run_layer(H2hi, H2lo, 0, HDIM, W_k23 + 16384, b_k23 + 128, W_q23 + 16384, b_q23 + 128,
              W_v23 + 16384, b_v23 + 128, a_rel23 + 16384, m_rel23 + 16384,
              p_rel23 + 4, W_a23 + 16384, b_a23 + 128,
              skip23 + 1, H2hi, H2lo, H1hi, H1lo);

    // global mean pool (batch sorted)
    hipMemsetAsync(S, 0, (size_t)N_GRAPHS_C * HDIM * sizeof(float), stream);
    dim3 pg(N_GRAPHS_C, 8);
    pool_kernel<<<pg, HDIM, 0, stream>>>(H1hi, H1lo, batch, S, N);
    pool_finalize<<<N_GRAPHS_C, HDIM, 0, stream>>>(S, batch, GM, N);

    // MLP
    {
        dim3 g1(128 / BN, 1);
        gemm_bias_kernel<<<g1, 256, 0, stream>>>(GM, 128, W_m1, 128, b_m1, M1, 128,
                                                 N_GRAPHS_C, 128, 1);
        dim3 g2(256 / BN, 1);
        gemm_bias_kernel<<<g2, 256, 0, stream>>>(M1, 128, W_m2, 256, b_m2,
                                                 (float*)d_out, 256, N_GRAPHS_C, 128, 0);
    }
}